// Round 1
// baseline (5813.895 us; speedup 1.0000x reference)
//
#include <hip/hip_runtime.h>
#include <cmath>

#define THETA 10.0f

// Compute the truncated SLAYER alpha kernel (tau=10, mult=1, K=77) into LDS,
// in double precision to bit-match numpy's f64 computation -> f32 cast.
__device__ __forceinline__ void init_srm(float* srm) {
    int tid = threadIdx.x;
    if (tid < 77) {
        double td = (double)tid;
        srm[tid] = (float)(td / 10.0 * exp(1.0 - td / 10.0));
    }
    __syncthreads();
}

// ---------------------------------------------------------------------------
// 1) PSP of the raw input, with layout transpose [m][T] -> [T][M]
// ---------------------------------------------------------------------------
__global__ void psp_in_kernel(const float* __restrict__ x, float* __restrict__ out,
                              int M, int T) {
    __shared__ float srm[77];
    init_srm(srm);
    int t = blockIdx.y;
    int m = blockIdx.x * blockDim.x + threadIdx.x;
    if (m >= M) return;
    const float* row = x + (size_t)m * T;
    int smax = t < 76 ? t : 76;
    float acc = 0.f;
    for (int s = 0; s <= smax; ++s) acc = fmaf(row[t - s], srm[s], acc);
    out[(size_t)t * M + m] = acc;
}

// ---------------------------------------------------------------------------
// 2) PSP, time-major -> time-major
// ---------------------------------------------------------------------------
__global__ void psp_kernel(const float* __restrict__ in, float* __restrict__ out,
                           int M) {
    __shared__ float srm[77];
    init_srm(srm);
    int t = blockIdx.y;
    int m = blockIdx.x * blockDim.x + threadIdx.x;
    if (m >= M) return;
    int smax = t < 76 ? t : 76;
    float acc = 0.f;
    for (int s = 0; s <= smax; ++s)
        acc = fmaf(in[(size_t)(t - s) * M + m], srm[s], acc);
    out[(size_t)t * M + m] = acc;
}

// ---------------------------------------------------------------------------
// 3) fused PSP + 2x2 sum-pool * 2.75  (pool2(psp(s)) with linearity)
// ---------------------------------------------------------------------------
__global__ void psppool_kernel(const float* __restrict__ in, float* __restrict__ out,
                               int NC, int Hin, int Win) {
    __shared__ float srm[77];
    init_srm(srm);
    int Ho = Hin >> 1, Wo = Win >> 1;
    int Mout = NC * Ho * Wo;
    int Min = NC * Hin * Win;
    int t = blockIdx.y;
    int mo = blockIdx.x * blockDim.x + threadIdx.x;
    if (mo >= Mout) return;
    int X = mo % Wo;
    int Y = (mo / Wo) % Ho;
    int nc = mo / (Wo * Ho);
    int base = nc * Hin * Win + (2 * Y) * Win + 2 * X;
    int smax = t < 76 ? t : 76;
    float acc = 0.f;
    for (int s = 0; s <= smax; ++s) {
        const float* p = in + (size_t)(t - s) * Min + base;
        float v = (p[0] + p[1]) + (p[Win] + p[Win + 1]);
        acc = fmaf(srm[s], v, acc);
    }
    out[(size_t)t * Mout + mo] = acc * 2.75f;  // 1.1*theta/4
}

// ---------------------------------------------------------------------------
// 4) spatial conv per time step (time-major, weights (O,I,K,K))
// ---------------------------------------------------------------------------
__global__ void conv_kernel(const float* __restrict__ in, const float* __restrict__ w,
                            float* __restrict__ out, int N_, int Cin, int Hin, int Win,
                            int Cout, int K, int pad) {
    int Hout = Hin + 2 * pad - K + 1;
    int Wout = Win + 2 * pad - K + 1;
    int Mout = N_ * Cout * Hout * Wout;
    int Min = N_ * Cin * Hin * Win;
    int t = blockIdx.y;
    int mo = blockIdx.x * blockDim.x + threadIdx.x;
    if (mo >= Mout) return;
    int x = mo % Wout;
    int y = (mo / Wout) % Hout;
    int o = (mo / (Wout * Hout)) % Cout;
    int n = mo / (Wout * Hout * Cout);
    const float* inp = in + (size_t)t * Min + (size_t)n * Cin * Hin * Win;
    float acc = 0.f;
    for (int i = 0; i < Cin; ++i) {
        const float* ip = inp + i * Hin * Win;
        const float* wp = w + ((size_t)o * Cin + i) * K * K;
        for (int ky = 0; ky < K; ++ky) {
            int iy = y + ky - pad;
            if ((unsigned)iy >= (unsigned)Hin) continue;
            for (int kx = 0; kx < K; ++kx) {
                int ix = x + kx - pad;
                if ((unsigned)ix >= (unsigned)Win) continue;
                acc = fmaf(ip[iy * Win + ix], wp[ky * K + kx], acc);
            }
        }
    }
    out[(size_t)t * Mout + mo] = acc;
}

// ---------------------------------------------------------------------------
// 5) LIF spike scan with refractory feedback, in-place on u (time-major).
//    REF[k] = -2*theta * k * exp(1-k), k=0..10 (REF[0]=0).
// ---------------------------------------------------------------------------
__global__ void spike_kernel(float* __restrict__ u, int M, int T) {
    int m = blockIdx.x * blockDim.x + threadIdx.x;
    if (m >= M) return;
    float ref[11];
#pragma unroll
    for (int k = 0; k < 11; ++k)
        ref[k] = (float)(-20.0 * (double)k * exp(1.0 - (double)k));
    float r[11];
#pragma unroll
    for (int k = 0; k < 11; ++k) r[k] = 0.f;
    for (int t = 0; t < T; ++t) {
        size_t idx = (size_t)t * M + m;
        float ue = u[idx] + r[0];
        float s = (ue >= THETA) ? 1.0f : 0.0f;
        u[idx] = s;
        // buf[k] += s*REF[k]; shift left  ==>  r'[k] = r[k+1] + s*REF[k+1]
        // (s in {0,1} so fma == mul+add exactly)
#pragma unroll
        for (int k = 0; k < 10; ++k) r[k] = fmaf(s, ref[k + 1], r[k + 1]);
        // r[10] stays 0
    }
}

// ---------------------------------------------------------------------------
// 6) dense: einsum nchwt,ochw->not  (per (t,n) block; 4096-long dot x 10)
// ---------------------------------------------------------------------------
__global__ void dense_kernel(const float* __restrict__ p, const float* __restrict__ wfc,
                             float* __restrict__ out) {
    int n = blockIdx.x;   // 0..7
    int t = blockIdx.y;   // 0..299
    int tid = threadIdx.x;
    const float* row = p + ((size_t)t * 8 + n) * 4096;
    float acc[10];
#pragma unroll
    for (int o = 0; o < 10; ++o) acc[o] = 0.f;
    for (int j = tid; j < 4096; j += 256) {
        float v = row[j];
#pragma unroll
        for (int o = 0; o < 10; ++o) acc[o] = fmaf(v, wfc[o * 4096 + j], acc[o]);
    }
    __shared__ float red[4][10];
#pragma unroll
    for (int o = 0; o < 10; ++o) {
        float a = acc[o];
        for (int off = 32; off > 0; off >>= 1) a += __shfl_down(a, off, 64);
        acc[o] = a;
    }
    int wave = tid >> 6, lane = tid & 63;
    if (lane == 0) {
#pragma unroll
        for (int o = 0; o < 10; ++o) red[wave][o] = acc[o];
    }
    __syncthreads();
    if (tid < 10) {
        float a = (red[0][tid] + red[1][tid]) + (red[2][tid] + red[3][tid]);
        out[((size_t)t * 8 + n) * 10 + tid] = a;
    }
}

// ---------------------------------------------------------------------------
// 7) final spike scan, writes d_out in reference layout (n,10,1,1,T)
// ---------------------------------------------------------------------------
__global__ void spike_out_kernel(const float* __restrict__ u, float* __restrict__ out,
                                 int M, int T) {
    int m = blockIdx.x * blockDim.x + threadIdx.x;
    if (m >= M) return;
    float ref[11];
#pragma unroll
    for (int k = 0; k < 11; ++k)
        ref[k] = (float)(-20.0 * (double)k * exp(1.0 - (double)k));
    float r[11];
#pragma unroll
    for (int k = 0; k < 11; ++k) r[k] = 0.f;
    for (int t = 0; t < T; ++t) {
        float ue = u[(size_t)t * M + m] + r[0];
        float s = (ue >= THETA) ? 1.0f : 0.0f;
        out[(size_t)m * T + t] = s;
#pragma unroll
        for (int k = 0; k < 10; ++k) r[k] = fmaf(s, ref[k + 1], r[k + 1]);
    }
}

// ---------------------------------------------------------------------------
extern "C" void kernel_launch(void* const* d_in, const int* in_sizes, int n_in,
                              void* d_out, int out_size, void* d_ws, size_t ws_size,
                              hipStream_t stream) {
    const float* x   = (const float*)d_in[0];  // (8,2,34,34,300)
    const float* w1  = (const float*)d_in[1];  // (16,2,5,5,1)
    const float* w2  = (const float*)d_in[2];  // (32,16,3,3,1)
    const float* w3  = (const float*)d_in[3];  // (64,32,3,3,1)
    const float* wfc = (const float*)d_in[4];  // (10,64,8,8)
    float* outp = (float*)d_out;               // (8,10,1,1,300)

    // ping-pong slots in workspace (floats): B = 39,321,600 ; A = 19,660,800
    float* slotB = (float*)d_ws;
    float* slotA = slotB + 39321600;
    const int T = 300;
    dim3 blk(256);

    // 1. p0 = psp(x) transpose -> slotA   M0 = 8*2*34*34 = 18496
    psp_in_kernel<<<dim3(73, T), blk, 0, stream>>>(x, slotA, 18496, T);
    // 2. u1 = conv(p0, w1, pad=1) -> slotB   (8,16,32,32): M=131072
    conv_kernel<<<dim3(512, T), blk, 0, stream>>>(slotA, w1, slotB, 8, 2, 34, 34, 16, 5, 1);
    // 3. s1 = spike(u1) in-place
    spike_kernel<<<dim3(512), blk, 0, stream>>>(slotB, 131072, T);
    // 4. u2 = pool(psp(s1)) -> slotA   (8,16,16,16): M=32768
    psppool_kernel<<<dim3(128, T), blk, 0, stream>>>(slotB, slotA, 8 * 16, 32, 32);
    // 5. s2 = spike(u2)
    spike_kernel<<<dim3(128), blk, 0, stream>>>(slotA, 32768, T);
    // 6. p2 = psp(s2) -> slotB
    psp_kernel<<<dim3(128, T), blk, 0, stream>>>(slotA, slotB, 32768);
    // 7. u3 = conv(p2, w2, pad=1) -> slotA   (8,32,16,16): M=65536
    conv_kernel<<<dim3(256, T), blk, 0, stream>>>(slotB, w2, slotA, 8, 16, 16, 16, 32, 3, 1);
    // 8. s3 = spike(u3)
    spike_kernel<<<dim3(256), blk, 0, stream>>>(slotA, 65536, T);
    // 9. u4 = pool(psp(s3)) -> slotB   (8,32,8,8): M=16384
    psppool_kernel<<<dim3(64, T), blk, 0, stream>>>(slotA, slotB, 8 * 32, 16, 16);
    // 10. s4 = spike(u4)
    spike_kernel<<<dim3(64), blk, 0, stream>>>(slotB, 16384, T);
    // 11. p4 = psp(s4) -> slotA
    psp_kernel<<<dim3(64, T), blk, 0, stream>>>(slotB, slotA, 16384);
    // 12. u5 = conv(p4, w3, pad=1) -> slotB   (8,64,8,8): M=32768
    conv_kernel<<<dim3(128, T), blk, 0, stream>>>(slotA, w3, slotB, 8, 32, 8, 8, 64, 3, 1);
    // 13. s5 = spike(u5)
    spike_kernel<<<dim3(128), blk, 0, stream>>>(slotB, 32768, T);
    // 14. p5 = psp(s5) -> slotA
    psp_kernel<<<dim3(128, T), blk, 0, stream>>>(slotB, slotA, 32768);
    // 15. u6 = dense(p5, wfc) -> slotB  [T][8][10]
    dense_kernel<<<dim3(8, T), blk, 0, stream>>>(slotA, wfc, slotB);
    // 16. out = spike(u6), written in reference (n,o,t) layout
    spike_out_kernel<<<dim3(2), dim3(64), 0, stream>>>(slotB, outp, 80, T);
}

// Round 3
// 3508.855 us; speedup vs baseline: 1.6569x; 1.6569x over previous
//
#include <hip/hip_runtime.h>
#include <cmath>

#define THETA 10.0f

// Truncated SLAYER alpha kernel (tau=10, mult=1, K=77), computed in double
// to bit-match numpy's f64 -> f32 path.
__device__ __forceinline__ void init_srm(float* srm) {
    int tid = threadIdx.x;
    if (tid < 77) {
        double td = (double)tid;
        srm[tid] = (float)(td / 10.0 * exp(1.0 - td / 10.0));
    }
    __syncthreads();
}

// ---------------------------------------------------------------------------
// 1) PSP of the raw input, layout transpose [m][T] -> [T][M], t-tiled x4.
//    Per output t: acc = sum_{s=0..min(t,76)} x[t-s]*srm[s], s ascending.
// ---------------------------------------------------------------------------
__global__ void psp_in_kernel(const float* __restrict__ x, float* __restrict__ out,
                              int M, int T) {
    __shared__ float srm[77];
    init_srm(srm);
    int tb = blockIdx.y * 4;
    int m = blockIdx.x * blockDim.x + threadIdx.x;
    if (m >= M) return;
    const float* row = x + (size_t)m * T;
    float acc[4] = {0.f, 0.f, 0.f, 0.f};
    int ulo = tb - 76; if (ulo < 0) ulo = 0;
    for (int u = tb + 3; u >= ulo; --u) {
        float v = row[u];
#pragma unroll
        for (int j = 0; j < 4; ++j) {
            int s = tb + j - u;                  // uniform across lanes
            if (s >= 0 && s <= 76) acc[j] = fmaf(v, srm[s], acc[j]);
        }
    }
#pragma unroll
    for (int j = 0; j < 4; ++j) out[(size_t)(tb + j) * M + m] = acc[j];
}

// ---------------------------------------------------------------------------
// 2) PSP, time-major -> time-major, t-tiled x4 (ILP 4, loads shared).
// ---------------------------------------------------------------------------
__global__ void psp_kernel(const float* __restrict__ in, float* __restrict__ out,
                           int M) {
    __shared__ float srm[77];
    init_srm(srm);
    int tb = blockIdx.y * 4;
    int m = blockIdx.x * blockDim.x + threadIdx.x;
    if (m >= M) return;
    float acc[4] = {0.f, 0.f, 0.f, 0.f};
    int ulo = tb - 76; if (ulo < 0) ulo = 0;
    for (int u = tb + 3; u >= ulo; --u) {
        float v = in[(size_t)u * M + m];
#pragma unroll
        for (int j = 0; j < 4; ++j) {
            int s = tb + j - u;
            if (s >= 0 && s <= 76) acc[j] = fmaf(v, srm[s], acc[j]);
        }
    }
#pragma unroll
    for (int j = 0; j < 4; ++j) out[(size_t)(tb + j) * M + m] = acc[j];
}

// ---------------------------------------------------------------------------
// 3) fused PSP + 2x2 sum-pool * 2.75, t-tiled x4. Per-tap order matches the
//    round-1 kernel that validated bit-exact: quad-sum then fma(srm).
// ---------------------------------------------------------------------------
__global__ void psppool_kernel(const float* __restrict__ in, float* __restrict__ out,
                               int NC, int Hin, int Win) {
    __shared__ float srm[77];
    init_srm(srm);
    int Ho = Hin >> 1, Wo = Win >> 1;
    int Mout = NC * Ho * Wo;
    int Min = NC * Hin * Win;
    int tb = blockIdx.y * 4;
    int mo = blockIdx.x * blockDim.x + threadIdx.x;
    if (mo >= Mout) return;
    int X = mo % Wo;
    int Y = (mo / Wo) % Ho;
    int nc = mo / (Wo * Ho);
    int base = nc * Hin * Win + (2 * Y) * Win + 2 * X;
    float acc[4] = {0.f, 0.f, 0.f, 0.f};
    int ulo = tb - 76; if (ulo < 0) ulo = 0;
    for (int u = tb + 3; u >= ulo; --u) {
        const float* p = in + (size_t)u * Min + base;
        float v = (p[0] + p[1]) + (p[Win] + p[Win + 1]);
#pragma unroll
        for (int j = 0; j < 4; ++j) {
            int s = tb + j - u;
            if (s >= 0 && s <= 76) acc[j] = fmaf(srm[s], v, acc[j]);
        }
    }
#pragma unroll
    for (int j = 0; j < 4; ++j)
        out[(size_t)(tb + j) * Mout + mo] = acc[j] * 2.75f;  // 1.1*theta/4
}

// ---------------------------------------------------------------------------
// 4) register-tiled conv: each thread computes ALL COUT channels at one
//    (t,n,y,x). Input value loaded once, reused COUT times; weight reads are
//    wave-uniform (scalar pipe). Per-o accumulation order (i,ky,kx) identical
//    to the validated round-1 kernel -> bit-exact.
// ---------------------------------------------------------------------------
template <int CIN, int K, int COUT>
__global__ void conv_tiled(const float* __restrict__ in, const float* __restrict__ w,
                           float* __restrict__ out, int NB, int Hin, int Win,
                           int Hout, int Wout, int pad) {
    int t = blockIdx.y;
    int sp = blockIdx.x * blockDim.x + threadIdx.x;  // over NB*Hout*Wout
    int total = NB * Hout * Wout;
    if (sp >= total) return;
    int x = sp % Wout;
    int y = (sp / Wout) % Hout;
    int n = sp / (Wout * Hout);
    const float* ip0 = in + ((size_t)t * NB + n) * CIN * Hin * Win;
    float acc[COUT];
#pragma unroll
    for (int o = 0; o < COUT; ++o) acc[o] = 0.f;
    for (int i = 0; i < CIN; ++i) {
        const float* ip = ip0 + i * Hin * Win;
        const float* wp = w + i * K * K;
        for (int ky = 0; ky < K; ++ky) {
            int iy = y + ky - pad;
            if ((unsigned)iy >= (unsigned)Hin) continue;
            for (int kx = 0; kx < K; ++kx) {
                int ix = x + kx - pad;
                if ((unsigned)ix >= (unsigned)Win) continue;
                float v = ip[iy * Win + ix];
                const float* wpk = wp + ky * K + kx;
#pragma unroll
                for (int o = 0; o < COUT; ++o)
                    acc[o] = fmaf(v, wpk[o * CIN * K * K], acc[o]);
            }
        }
    }
    float* op = out + (((size_t)t * NB + n) * COUT) * Hout * Wout + y * Wout + x;
#pragma unroll
    for (int o = 0; o < COUT; ++o) op[(size_t)o * Hout * Wout] = acc[o];
}

// ---------------------------------------------------------------------------
// 5) LIF spike scan with refractory feedback, in-place on u (time-major).
// ---------------------------------------------------------------------------
__global__ void spike_kernel(float* __restrict__ u, int M, int T) {
    int m = blockIdx.x * blockDim.x + threadIdx.x;
    if (m >= M) return;
    float ref[11];
#pragma unroll
    for (int k = 0; k < 11; ++k)
        ref[k] = (float)(-20.0 * (double)k * exp(1.0 - (double)k));
    float r[11];
#pragma unroll
    for (int k = 0; k < 11; ++k) r[k] = 0.f;
    for (int t = 0; t < T; ++t) {
        size_t idx = (size_t)t * M + m;
        float ue = u[idx] + r[0];
        float s = (ue >= THETA) ? 1.0f : 0.0f;
        u[idx] = s;
#pragma unroll
        for (int k = 0; k < 10; ++k) r[k] = fmaf(s, ref[k + 1], r[k + 1]);
    }
}

// ---------------------------------------------------------------------------
// 6) dense: einsum nchwt,ochw->not  (per (t,n) block; 4096-long dot x 10)
// ---------------------------------------------------------------------------
__global__ void dense_kernel(const float* __restrict__ p, const float* __restrict__ wfc,
                             float* __restrict__ out) {
    int n = blockIdx.x;   // 0..7
    int t = blockIdx.y;   // 0..299
    int tid = threadIdx.x;
    const float* row = p + ((size_t)t * 8 + n) * 4096;
    float acc[10];
#pragma unroll
    for (int o = 0; o < 10; ++o) acc[o] = 0.f;
    for (int j = tid; j < 4096; j += 256) {
        float v = row[j];
#pragma unroll
        for (int o = 0; o < 10; ++o) acc[o] = fmaf(v, wfc[o * 4096 + j], acc[o]);
    }
    __shared__ float red[4][10];
#pragma unroll
    for (int o = 0; o < 10; ++o) {
        float a = acc[o];
        for (int off = 32; off > 0; off >>= 1) a += __shfl_down(a, off, 64);
        acc[o] = a;
    }
    int wave = tid >> 6, lane = tid & 63;
    if (lane == 0) {
#pragma unroll
        for (int o = 0; o < 10; ++o) red[wave][o] = acc[o];
    }
    __syncthreads();
    if (tid < 10) {
        float a = (red[0][tid] + red[1][tid]) + (red[2][tid] + red[3][tid]);
        out[((size_t)t * 8 + n) * 10 + tid] = a;
    }
}

// ---------------------------------------------------------------------------
// 7) final spike scan, writes d_out in reference layout (n,10,1,1,T)
// ---------------------------------------------------------------------------
__global__ void spike_out_kernel(const float* __restrict__ u, float* __restrict__ out,
                                 int M, int T) {
    int m = blockIdx.x * blockDim.x + threadIdx.x;
    if (m >= M) return;
    float ref[11];
#pragma unroll
    for (int k = 0; k < 11; ++k)
        ref[k] = (float)(-20.0 * (double)k * exp(1.0 - (double)k));
    float r[11];
#pragma unroll
    for (int k = 0; k < 11; ++k) r[k] = 0.f;
    for (int t = 0; t < T; ++t) {
        float ue = u[(size_t)t * M + m] + r[0];
        float s = (ue >= THETA) ? 1.0f : 0.0f;
        out[(size_t)m * T + t] = s;
#pragma unroll
        for (int k = 0; k < 10; ++k) r[k] = fmaf(s, ref[k + 1], r[k + 1]);
    }
}

// ---------------------------------------------------------------------------
extern "C" void kernel_launch(void* const* d_in, const int* in_sizes, int n_in,
                              void* d_out, int out_size, void* d_ws, size_t ws_size,
                              hipStream_t stream) {
    const float* x   = (const float*)d_in[0];  // (8,2,34,34,300)
    const float* w1  = (const float*)d_in[1];  // (16,2,5,5,1)
    const float* w2  = (const float*)d_in[2];  // (32,16,3,3,1)
    const float* w3  = (const float*)d_in[3];  // (64,32,3,3,1)
    const float* wfc = (const float*)d_in[4];  // (10,64,8,8)
    float* outp = (float*)d_out;               // (8,10,1,1,300)

    float* slotB = (float*)d_ws;               // 39,321,600 floats
    float* slotA = slotB + 39321600;           // 19,660,800 floats
    const int T = 300;
    dim3 blk(256);

    // 1. p0 = psp(x) transpose -> slotA   M0 = 18496
    psp_in_kernel<<<dim3(73, 75), blk, 0, stream>>>(x, slotA, 18496, T);
    // 2. u1 = conv(p0, w1, pad=1) -> slotB   (8,16,32,32), spatial=8192
    conv_tiled<2, 5, 16><<<dim3(32, T), blk, 0, stream>>>(slotA, w1, slotB, 8, 34, 34, 32, 32, 1);
    // 3. s1 = spike(u1) in-place, M=131072
    spike_kernel<<<dim3(512), blk, 0, stream>>>(slotB, 131072, T);
    // 4. u2 = pool(psp(s1)) -> slotA   M=32768
    psppool_kernel<<<dim3(128, 75), blk, 0, stream>>>(slotB, slotA, 8 * 16, 32, 32);
    // 5. s2 = spike(u2)
    spike_kernel<<<dim3(128), blk, 0, stream>>>(slotA, 32768, T);
    // 6. p2 = psp(s2) -> slotB
    psp_kernel<<<dim3(128, 75), blk, 0, stream>>>(slotA, slotB, 32768);
    // 7. u3 = conv(p2, w2, pad=1) -> slotA   (8,32,16,16), spatial=2048
    conv_tiled<16, 3, 32><<<dim3(8, T), blk, 0, stream>>>(slotB, w2, slotA, 8, 16, 16, 16, 16, 1);
    // 8. s3 = spike(u3), M=65536
    spike_kernel<<<dim3(256), blk, 0, stream>>>(slotA, 65536, T);
    // 9. u4 = pool(psp(s3)) -> slotB   M=16384
    psppool_kernel<<<dim3(64, 75), blk, 0, stream>>>(slotA, slotB, 8 * 32, 16, 16);
    // 10. s4 = spike(u4)
    spike_kernel<<<dim3(64), blk, 0, stream>>>(slotB, 16384, T);
    // 11. p4 = psp(s4) -> slotA
    psp_kernel<<<dim3(64, 75), blk, 0, stream>>>(slotB, slotA, 16384);
    // 12. u5 = conv(p4, w3, pad=1) -> slotB   (8,64,8,8), spatial=512
    conv_tiled<32, 3, 64><<<dim3(2, T), blk, 0, stream>>>(slotA, w3, slotB, 8, 8, 8, 8, 8, 1);
    // 13. s5 = spike(u5), M=32768
    spike_kernel<<<dim3(128), blk, 0, stream>>>(slotB, 32768, T);
    // 14. p5 = psp(s5) -> slotA
    psp_kernel<<<dim3(128, 75), blk, 0, stream>>>(slotB, slotA, 32768);
    // 15. u6 = dense(p5, wfc) -> slotB  [T][8][10]
    dense_kernel<<<dim3(8, T), blk, 0, stream>>>(slotA, wfc, slotB);
    // 16. out = spike(u6), reference (n,o,t) layout
    spike_out_kernel<<<dim3(2), dim3(64), 0, stream>>>(slotB, outp, 80, T);
}

// Round 6
// 1591.642 us; speedup vs baseline: 3.6528x; 2.2046x over previous
//
#include <hip/hip_runtime.h>
#include <cmath>

#define THETA 10.0f

// Truncated SLAYER alpha kernel (tau=10, mult=1, K=77), computed in double
// to bit-match numpy's f64 -> f32 path.
__device__ __forceinline__ void init_srm(float* srm) {
    int tid = threadIdx.x;
    if (tid < 77) {
        double td = (double)tid;
        srm[tid] = (float)(td / 10.0 * exp(1.0 - td / 10.0));
    }
    __syncthreads();
}

// ---------------------------------------------------------------------------
// 0) coalesced LDS tiled transpose: in[M][T] -> out[T][M]
// ---------------------------------------------------------------------------
__global__ void transpose_kernel(const float* __restrict__ in, float* __restrict__ out,
                                 int M, int T) {
    __shared__ float tile[32][33];
    int mBase = blockIdx.x * 32;
    int tBase = blockIdx.y * 32;
    int tx = threadIdx.x, ty = threadIdx.y;  // block (32,8)
    for (int i = ty; i < 32; i += 8) {
        int m = mBase + i, t = tBase + tx;
        if (m < M && t < T) tile[i][tx] = in[(size_t)m * T + t];
    }
    __syncthreads();
    for (int i = ty; i < 32; i += 8) {
        int t = tBase + i, m = mBase + tx;
        if (t < T && m < M) out[(size_t)t * M + m] = tile[tx][i];
    }
}

// ---------------------------------------------------------------------------
// 1) PSP, time-major -> time-major, t-tiled x TT (ILP TT, loads shared).
//    Per output t: acc = sum_{s=0..min(t,76)} in[t-s]*srm[s], s ascending
//    (u descends => s ascends for each j) -> bit-exact vs reference.
// ---------------------------------------------------------------------------
template <int TT>
__global__ void psp_kernel(const float* __restrict__ in, float* __restrict__ out,
                           int M) {
    __shared__ float srm[77];
    init_srm(srm);
    int tb = blockIdx.y * TT;
    int m = blockIdx.x * blockDim.x + threadIdx.x;
    if (m >= M) return;
    float acc[TT];
#pragma unroll
    for (int j = 0; j < TT; ++j) acc[j] = 0.f;
    int ulo = tb - 76; if (ulo < 0) ulo = 0;
    for (int u = tb + TT - 1; u >= ulo; --u) {
        float v = in[(size_t)u * M + m];
#pragma unroll
        for (int j = 0; j < TT; ++j) {
            int s = tb + j - u;
            if (s >= 0 && s <= 76) acc[j] = fmaf(v, srm[s], acc[j]);
        }
    }
#pragma unroll
    for (int j = 0; j < TT; ++j) out[(size_t)(tb + j) * M + m] = acc[j];
}

// ---------------------------------------------------------------------------
// 2) fused PSP + 2x2 sum-pool * 2.75, t-tiled x TT. Per-tap order matches the
//    validated kernel: quad-sum then fma(srm) -> bit-exact.
// ---------------------------------------------------------------------------
template <int TT>
__global__ void psppool_kernel(const float* __restrict__ in, float* __restrict__ out,
                               int NC, int Hin, int Win) {
    __shared__ float srm[77];
    init_srm(srm);
    int Ho = Hin >> 1, Wo = Win >> 1;
    int Mout = NC * Ho * Wo;
    int Min = NC * Hin * Win;
    int tb = blockIdx.y * TT;
    int mo = blockIdx.x * blockDim.x + threadIdx.x;
    if (mo >= Mout) return;
    int X = mo % Wo;
    int Y = (mo / Wo) % Ho;
    int nc = mo / (Wo * Ho);
    int base = nc * Hin * Win + (2 * Y) * Win + 2 * X;
    float acc[TT];
#pragma unroll
    for (int j = 0; j < TT; ++j) acc[j] = 0.f;
    int ulo = tb - 76; if (ulo < 0) ulo = 0;
    for (int u = tb + TT - 1; u >= ulo; --u) {
        const float* p = in + (size_t)u * Min + base;
        float v = (p[0] + p[1]) + (p[Win] + p[Win + 1]);
#pragma unroll
        for (int j = 0; j < TT; ++j) {
            int s = tb + j - u;
            if (s >= 0 && s <= 76) acc[j] = fmaf(srm[s], v, acc[j]);
        }
    }
#pragma unroll
    for (int j = 0; j < TT; ++j)
        out[(size_t)(tb + j) * Mout + mo] = acc[j] * 2.75f;  // 1.1*theta/4
}

// ---------------------------------------------------------------------------
// 3) register-tiled conv: each thread computes ALL COUT channels at one
//    (t,n,y,x). Per-o accumulation order (i,ky,kx) identical -> bit-exact.
// ---------------------------------------------------------------------------
template <int CIN, int K, int COUT>
__global__ void conv_tiled(const float* __restrict__ in, const float* __restrict__ w,
                           float* __restrict__ out, int NB, int Hin, int Win,
                           int Hout, int Wout, int pad) {
    int t = blockIdx.y;
    int sp = blockIdx.x * blockDim.x + threadIdx.x;  // over NB*Hout*Wout
    int total = NB * Hout * Wout;
    if (sp >= total) return;
    int x = sp % Wout;
    int y = (sp / Wout) % Hout;
    int n = sp / (Wout * Hout);
    const float* ip0 = in + ((size_t)t * NB + n) * CIN * Hin * Win;
    float acc[COUT];
#pragma unroll
    for (int o = 0; o < COUT; ++o) acc[o] = 0.f;
    for (int i = 0; i < CIN; ++i) {
        const float* ip = ip0 + i * Hin * Win;
        const float* wp = w + i * K * K;
        for (int ky = 0; ky < K; ++ky) {
            int iy = y + ky - pad;
            if ((unsigned)iy >= (unsigned)Hin) continue;
            for (int kx = 0; kx < K; ++kx) {
                int ix = x + kx - pad;
                if ((unsigned)ix >= (unsigned)Win) continue;
                float v = ip[iy * Win + ix];
                const float* wpk = wp + ky * K + kx;
#pragma unroll
                for (int o = 0; o < COUT; ++o)
                    acc[o] = fmaf(v, wpk[o * CIN * K * K], acc[o]);
            }
        }
    }
    float* op = out + (((size_t)t * NB + n) * COUT) * Hout * Wout + y * Wout + x;
#pragma unroll
    for (int o = 0; o < COUT; ++o) op[(size_t)o * Hout * Wout] = acc[o];
}

// ---------------------------------------------------------------------------
// 4) LIF spike scan with refractory feedback, in-place on u (time-major).
// ---------------------------------------------------------------------------
__global__ void spike_kernel(float* __restrict__ u, int M, int T) {
    int m = blockIdx.x * blockDim.x + threadIdx.x;
    if (m >= M) return;
    float ref[11];
#pragma unroll
    for (int k = 0; k < 11; ++k)
        ref[k] = (float)(-20.0 * (double)k * exp(1.0 - (double)k));
    float r[11];
#pragma unroll
    for (int k = 0; k < 11; ++k) r[k] = 0.f;
    for (int t = 0; t < T; ++t) {
        size_t idx = (size_t)t * M + m;
        float ue = u[idx] + r[0];
        float s = (ue >= THETA) ? 1.0f : 0.0f;
        u[idx] = s;
#pragma unroll
        for (int k = 0; k < 10; ++k) r[k] = fmaf(s, ref[k + 1], r[k + 1]);
    }
}

// ---------------------------------------------------------------------------
// 5) dense: einsum nchwt,ochw->not  (per (t,n) block; 4096-long dot x 10)
// ---------------------------------------------------------------------------
__global__ void dense_kernel(const float* __restrict__ p, const float* __restrict__ wfc,
                             float* __restrict__ out) {
    int n = blockIdx.x;   // 0..7
    int t = blockIdx.y;   // 0..299
    int tid = threadIdx.x;
    const float* row = p + ((size_t)t * 8 + n) * 4096;
    float acc[10];
#pragma unroll
    for (int o = 0; o < 10; ++o) acc[o] = 0.f;
    for (int j = tid; j < 4096; j += 256) {
        float v = row[j];
#pragma unroll
        for (int o = 0; o < 10; ++o) acc[o] = fmaf(v, wfc[o * 4096 + j], acc[o]);
    }
    __shared__ float red[4][10];
#pragma unroll
    for (int o = 0; o < 10; ++o) {
        float a = acc[o];
        for (int off = 32; off > 0; off >>= 1) a += __shfl_down(a, off, 64);
        acc[o] = a;
    }
    int wave = tid >> 6, lane = tid & 63;
    if (lane == 0) {
#pragma unroll
        for (int o = 0; o < 10; ++o) red[wave][o] = acc[o];
    }
    __syncthreads();
    if (tid < 10) {
        float a = (red[0][tid] + red[1][tid]) + (red[2][tid] + red[3][tid]);
        out[((size_t)t * 8 + n) * 10 + tid] = a;
    }
}

// ---------------------------------------------------------------------------
// 6) final spike scan, writes d_out in reference layout (n,10,1,1,T)
// ---------------------------------------------------------------------------
__global__ void spike_out_kernel(const float* __restrict__ u, float* __restrict__ out,
                                 int M, int T) {
    int m = blockIdx.x * blockDim.x + threadIdx.x;
    if (m >= M) return;
    float ref[11];
#pragma unroll
    for (int k = 0; k < 11; ++k)
        ref[k] = (float)(-20.0 * (double)k * exp(1.0 - (double)k));
    float r[11];
#pragma unroll
    for (int k = 0; k < 11; ++k) r[k] = 0.f;
    for (int t = 0; t < T; ++t) {
        float ue = u[(size_t)t * M + m] + r[0];
        float s = (ue >= THETA) ? 1.0f : 0.0f;
        out[(size_t)m * T + t] = s;
#pragma unroll
        for (int k = 0; k < 10; ++k) r[k] = fmaf(s, ref[k + 1], r[k + 1]);
    }
}

// ---------------------------------------------------------------------------
extern "C" void kernel_launch(void* const* d_in, const int* in_sizes, int n_in,
                              void* d_out, int out_size, void* d_ws, size_t ws_size,
                              hipStream_t stream) {
    const float* x   = (const float*)d_in[0];  // (8,2,34,34,300)
    const float* w1  = (const float*)d_in[1];  // (16,2,5,5,1)
    const float* w2  = (const float*)d_in[2];  // (32,16,3,3,1)
    const float* w3  = (const float*)d_in[3];  // (64,32,3,3,1)
    const float* wfc = (const float*)d_in[4];  // (10,64,8,8)
    float* outp = (float*)d_out;               // (8,10,1,1,300)

    float* slotB = (float*)d_ws;               // 39,321,600 floats
    float* slotA = slotB + 39321600;           // 19,660,800 floats
    const int T = 300;
    dim3 blk(256);
    constexpr int TT = 20;                      // 300 = 15 * 20, no tail

    // 0. xT = transpose(x): [18496][300] -> [300][18496], into slotB
    transpose_kernel<<<dim3(578, 10), dim3(32, 8), 0, stream>>>(x, slotB, 18496, T);
    // 1. p0 = psp(xT) -> slotA   M0 = 18496
    psp_kernel<TT><<<dim3(73, 15), blk, 0, stream>>>(slotB, slotA, 18496);
    // 2. u1 = conv(p0, w1, pad=1) -> slotB   (8,16,32,32), spatial=8192
    conv_tiled<2, 5, 16><<<dim3(32, T), blk, 0, stream>>>(slotA, w1, slotB, 8, 34, 34, 32, 32, 1);
    // 3. s1 = spike(u1) in-place, M=131072
    spike_kernel<<<dim3(512), blk, 0, stream>>>(slotB, 131072, T);
    // 4. u2 = pool(psp(s1)) -> slotA   M=32768
    psppool_kernel<TT><<<dim3(128, 15), blk, 0, stream>>>(slotB, slotA, 8 * 16, 32, 32);
    // 5. s2 = spike(u2)
    spike_kernel<<<dim3(128), blk, 0, stream>>>(slotA, 32768, T);
    // 6. p2 = psp(s2) -> slotB
    psp_kernel<TT><<<dim3(128, 15), blk, 0, stream>>>(slotA, slotB, 32768);
    // 7. u3 = conv(p2, w2, pad=1) -> slotA   (8,32,16,16), spatial=2048
    conv_tiled<16, 3, 32><<<dim3(8, T), blk, 0, stream>>>(slotB, w2, slotA, 8, 16, 16, 16, 16, 1);
    // 8. s3 = spike(u3), M=65536
    spike_kernel<<<dim3(256), blk, 0, stream>>>(slotA, 65536, T);
    // 9. u4 = pool(psp(s3)) -> slotB   M=16384
    psppool_kernel<TT><<<dim3(64, 15), blk, 0, stream>>>(slotA, slotB, 8 * 32, 16, 16);
    // 10. s4 = spike(u4)
    spike_kernel<<<dim3(64), blk, 0, stream>>>(slotB, 16384, T);
    // 11. p4 = psp(s4) -> slotA
    psp_kernel<TT><<<dim3(64, 15), blk, 0, stream>>>(slotB, slotA, 16384);
    // 12. u5 = conv(p4, w3, pad=1) -> slotB   (8,64,8,8), spatial=512
    conv_tiled<32, 3, 64><<<dim3(2, T), blk, 0, stream>>>(slotA, w3, slotB, 8, 8, 8, 8, 8, 1);
    // 13. s5 = spike(u5), M=32768
    spike_kernel<<<dim3(128), blk, 0, stream>>>(slotB, 32768, T);
    // 14. p5 = psp(s5) -> slotA
    psp_kernel<TT><<<dim3(128, 15), blk, 0, stream>>>(slotB, slotA, 32768);
    // 15. u6 = dense(p5, wfc) -> slotB  [T][8][10]
    dense_kernel<<<dim3(8, T), blk, 0, stream>>>(slotA, wfc, slotB);
    // 16. out = spike(u6), reference (n,o,t) layout
    spike_out_kernel<<<dim3(2), dim3(64), 0, stream>>>(slotB, outp, 80, T);
}

// Round 7
// 1354.706 us; speedup vs baseline: 4.2916x; 1.1749x over previous
//
#include <hip/hip_runtime.h>
#include <cmath>

#define THETA 10.0f

// Truncated SLAYER alpha kernel (tau=10, mult=1, K=77), computed in double
// to bit-match numpy's f64 -> f32 path.
__device__ __forceinline__ void init_srm(float* srm) {
    int tid = threadIdx.x;
    if (tid < 77) {
        double td = (double)tid;
        srm[tid] = (float)(td / 10.0 * exp(1.0 - td / 10.0));
    }
    __syncthreads();
}

// ---------------------------------------------------------------------------
// 0) coalesced LDS tiled transpose: in[M][T] -> out[T][M]
// ---------------------------------------------------------------------------
__global__ void transpose_kernel(const float* __restrict__ in, float* __restrict__ out,
                                 int M, int T) {
    __shared__ float tile[32][33];
    int mBase = blockIdx.x * 32;
    int tBase = blockIdx.y * 32;
    int tx = threadIdx.x, ty = threadIdx.y;  // block (32,8)
    for (int i = ty; i < 32; i += 8) {
        int m = mBase + i, t = tBase + tx;
        if (m < M && t < T) tile[i][tx] = in[(size_t)m * T + t];
    }
    __syncthreads();
    for (int i = ty; i < 32; i += 8) {
        int t = tBase + i, m = mBase + tx;
        if (t < T && m < M) out[(size_t)t * M + m] = tile[tx][i];
    }
}

// ---------------------------------------------------------------------------
// 1) PSP, time-major -> time-major, t-tiled x TT (ILP TT, loads shared).
//    Per output t: acc = sum_{s=0..min(t,76)} in[t-s]*srm[s], s ascending.
// ---------------------------------------------------------------------------
template <int TT>
__global__ void psp_kernel(const float* __restrict__ in, float* __restrict__ out,
                           int M) {
    __shared__ float srm[77];
    init_srm(srm);
    int tb = blockIdx.y * TT;
    int m = blockIdx.x * blockDim.x + threadIdx.x;
    if (m >= M) return;
    float acc[TT];
#pragma unroll
    for (int j = 0; j < TT; ++j) acc[j] = 0.f;
    int ulo = tb - 76; if (ulo < 0) ulo = 0;
    for (int u = tb + TT - 1; u >= ulo; --u) {
        float v = in[(size_t)u * M + m];
#pragma unroll
        for (int j = 0; j < TT; ++j) {
            int s = tb + j - u;
            if (s >= 0 && s <= 76) acc[j] = fmaf(v, srm[s], acc[j]);
        }
    }
#pragma unroll
    for (int j = 0; j < TT; ++j) out[(size_t)(tb + j) * M + m] = acc[j];
}

// ---------------------------------------------------------------------------
// 2) fused PSP + 2x2 sum-pool * 2.75, t-tiled x TT. Quad-sum then fma(srm),
//    validated bit-exact.
// ---------------------------------------------------------------------------
template <int TT>
__global__ void psppool_kernel(const float* __restrict__ in, float* __restrict__ out,
                               int NC, int Hin, int Win) {
    __shared__ float srm[77];
    init_srm(srm);
    int Ho = Hin >> 1, Wo = Win >> 1;
    int Mout = NC * Ho * Wo;
    int Min = NC * Hin * Win;
    int tb = blockIdx.y * TT;
    int mo = blockIdx.x * blockDim.x + threadIdx.x;
    if (mo >= Mout) return;
    int X = mo % Wo;
    int Y = (mo / Wo) % Ho;
    int nc = mo / (Wo * Ho);
    int base = nc * Hin * Win + (2 * Y) * Win + 2 * X;
    float acc[TT];
#pragma unroll
    for (int j = 0; j < TT; ++j) acc[j] = 0.f;
    int ulo = tb - 76; if (ulo < 0) ulo = 0;
    for (int u = tb + TT - 1; u >= ulo; --u) {
        const float* p = in + (size_t)u * Min + base;
        float v = (p[0] + p[1]) + (p[Win] + p[Win + 1]);
#pragma unroll
        for (int j = 0; j < TT; ++j) {
            int s = tb + j - u;
            if (s >= 0 && s <= 76) acc[j] = fmaf(srm[s], v, acc[j]);
        }
    }
#pragma unroll
    for (int j = 0; j < TT; ++j)
        out[(size_t)(tb + j) * Mout + mo] = acc[j] * 2.75f;  // 1.1*theta/4
}

// ---------------------------------------------------------------------------
// 3a) conv1: (2->16, 5x5, pad1, 34x34 -> 32x32), one block per (t,n).
//     Input tile + weights staged in LDS; per-o order (i,ky,kx) -> bit-exact.
// ---------------------------------------------------------------------------
__global__ __launch_bounds__(256) void conv1_lds(const float* __restrict__ in,
                                                 const float* __restrict__ w,
                                                 float* __restrict__ out) {
    __shared__ float s_in[2312];   // 2*34*34
    __shared__ float s_w[800];     // 16*2*25
    int n = blockIdx.x, t = blockIdx.y, tid = threadIdx.x;
    const float* src = in + ((size_t)t * 8 + n) * 2312;
    for (int i = tid; i < 2312; i += 256) s_in[i] = src[i];
    for (int i = tid; i < 800; i += 256) s_w[i] = w[i];
    __syncthreads();
    int x = tid & 31, yb0 = tid >> 5;  // 32 cols x 8 rows
    float* dst = out + ((size_t)t * 8 + n) * 16384;  // 16*32*32
    for (int yb = 0; yb < 4; ++yb) {
        int y = yb * 8 + yb0;
        float acc[16];
#pragma unroll
        for (int o = 0; o < 16; ++o) acc[o] = 0.f;
#pragma unroll
        for (int i = 0; i < 2; ++i) {
#pragma unroll
            for (int ky = 0; ky < 5; ++ky) {
                int iy = y + ky - 1;
                if ((unsigned)iy >= 34u) continue;
#pragma unroll
                for (int kx = 0; kx < 5; ++kx) {
                    int ix = x + kx - 1;
                    if ((unsigned)ix >= 34u) continue;
                    float v = s_in[i * 1156 + iy * 34 + ix];
                    const float* wp = &s_w[i * 25 + ky * 5 + kx];
#pragma unroll
                    for (int o = 0; o < 16; ++o)
                        acc[o] = fmaf(v, wp[o * 50], acc[o]);
                }
            }
        }
#pragma unroll
        for (int o = 0; o < 16; ++o) dst[o * 1024 + y * 32 + x] = acc[o];
    }
}

// ---------------------------------------------------------------------------
// 3b) conv2: (16->32, 3x3, pad1, 16x16 -> 16x16), one block per (t,n),
//     one output position per thread, acc[32].
// ---------------------------------------------------------------------------
__global__ __launch_bounds__(256) void conv2_lds(const float* __restrict__ in,
                                                 const float* __restrict__ w,
                                                 float* __restrict__ out) {
    __shared__ float s_in[4096];   // 16*16*16
    __shared__ float s_w[4608];    // 32*16*9
    int n = blockIdx.x, t = blockIdx.y, tid = threadIdx.x;
    const float* src = in + ((size_t)t * 8 + n) * 4096;
    for (int i = tid; i < 4096; i += 256) s_in[i] = src[i];
    for (int i = tid; i < 4608; i += 256) s_w[i] = w[i];
    __syncthreads();
    int x = tid & 15, y = tid >> 4;
    float acc[32];
#pragma unroll
    for (int o = 0; o < 32; ++o) acc[o] = 0.f;
    for (int i = 0; i < 16; ++i) {
#pragma unroll
        for (int ky = 0; ky < 3; ++ky) {
            int iy = y + ky - 1;
            if ((unsigned)iy >= 16u) continue;
#pragma unroll
            for (int kx = 0; kx < 3; ++kx) {
                int ix = x + kx - 1;
                if ((unsigned)ix >= 16u) continue;
                float v = s_in[i * 256 + iy * 16 + ix];
                const float* wp = &s_w[i * 9 + ky * 3 + kx];
#pragma unroll
                for (int o = 0; o < 32; ++o)
                    acc[o] = fmaf(v, wp[o * 144], acc[o]);
            }
        }
    }
    float* dst = out + ((size_t)t * 8 + n) * 8192;  // 32*256
#pragma unroll
    for (int o = 0; o < 32; ++o) dst[o * 256 + tid] = acc[o];
}

// ---------------------------------------------------------------------------
// 3c) conv3: (32->64, 3x3, pad1, 8x8 -> 8x8). Block = (t, 4 n's, half of
//     COUT); 64 positions per n, acc[32]. LDS: 32KB input + 36.8KB weights.
// ---------------------------------------------------------------------------
__global__ __launch_bounds__(256) void conv3_lds(const float* __restrict__ in,
                                                 const float* __restrict__ w,
                                                 float* __restrict__ out) {
    __shared__ float s_in[8192];   // 4n * 32*8*8
    __shared__ float s_w[9216];    // 32o * 32*9
    int n0 = blockIdx.x * 4, t = blockIdx.y, ob = blockIdx.z * 32;
    int tid = threadIdx.x;
    const float* src = in + ((size_t)t * 16384 + n0 * 2048);
    for (int i = tid; i < 8192; i += 256) s_in[i] = src[i];
    const float* wsrc = w + (size_t)ob * 288;
    for (int i = tid; i < 9216; i += 256) s_w[i] = wsrc[i];
    __syncthreads();
    int ln = tid >> 6;             // local n 0..3
    int pos = tid & 63;            // y*8+x
    int y = pos >> 3, x = pos & 7;
    const float* base = &s_in[ln * 2048];
    float acc[32];
#pragma unroll
    for (int o = 0; o < 32; ++o) acc[o] = 0.f;
    for (int i = 0; i < 32; ++i) {
#pragma unroll
        for (int ky = 0; ky < 3; ++ky) {
            int iy = y + ky - 1;
            if ((unsigned)iy >= 8u) continue;
#pragma unroll
            for (int kx = 0; kx < 3; ++kx) {
                int ix = x + kx - 1;
                if ((unsigned)ix >= 8u) continue;
                float v = base[i * 64 + iy * 8 + ix];
                const float* wp = &s_w[i * 9 + ky * 3 + kx];
#pragma unroll
                for (int o = 0; o < 32; ++o)
                    acc[o] = fmaf(v, wp[o * 288], acc[o]);
            }
        }
    }
    float* dst = out + (((size_t)t * 8 + n0 + ln) * 64 + ob) * 64;
#pragma unroll
    for (int o = 0; o < 32; ++o) dst[o * 64 + pos] = acc[o];
}

// ---------------------------------------------------------------------------
// 4) LIF spike scan, chunked: batch-load CH timesteps (independent loads,
//    one latency per CH steps), double-buffered. Arithmetic order unchanged.
//    T must be a multiple of CH (300 = 30*10).
// ---------------------------------------------------------------------------
template <int CH>
__global__ void spike_kernel(float* __restrict__ u, int M, int T) {
    int m = blockIdx.x * blockDim.x + threadIdx.x;
    if (m >= M) return;
    float ref[11];
#pragma unroll
    for (int k = 0; k < 11; ++k)
        ref[k] = (float)(-20.0 * (double)k * exp(1.0 - (double)k));
    float r[11];
#pragma unroll
    for (int k = 0; k < 11; ++k) r[k] = 0.f;
    float a[CH], b[CH];
#pragma unroll
    for (int j = 0; j < CH; ++j) a[j] = u[(size_t)j * M + m];
    int NC = T / CH;
    for (int c = 0; c < NC; ++c) {
        if (c + 1 < NC) {
#pragma unroll
            for (int j = 0; j < CH; ++j)
                b[j] = u[(size_t)((c + 1) * CH + j) * M + m];
        }
#pragma unroll
        for (int j = 0; j < CH; ++j) {
            float ue = a[j] + r[0];
            float s = (ue >= THETA) ? 1.0f : 0.0f;
            u[(size_t)(c * CH + j) * M + m] = s;
#pragma unroll
            for (int k = 0; k < 10; ++k) r[k] = fmaf(s, ref[k + 1], r[k + 1]);
        }
#pragma unroll
        for (int j = 0; j < CH; ++j) a[j] = b[j];
    }
}

// ---------------------------------------------------------------------------
// 5) dense: einsum nchwt,ochw->not  (per (t,n) block; 4096-long dot x 10)
// ---------------------------------------------------------------------------
__global__ void dense_kernel(const float* __restrict__ p, const float* __restrict__ wfc,
                             float* __restrict__ out) {
    int n = blockIdx.x;   // 0..7
    int t = blockIdx.y;   // 0..299
    int tid = threadIdx.x;
    const float* row = p + ((size_t)t * 8 + n) * 4096;
    float acc[10];
#pragma unroll
    for (int o = 0; o < 10; ++o) acc[o] = 0.f;
    for (int j = tid; j < 4096; j += 256) {
        float v = row[j];
#pragma unroll
        for (int o = 0; o < 10; ++o) acc[o] = fmaf(v, wfc[o * 4096 + j], acc[o]);
    }
    __shared__ float red[4][10];
#pragma unroll
    for (int o = 0; o < 10; ++o) {
        float a = acc[o];
        for (int off = 32; off > 0; off >>= 1) a += __shfl_down(a, off, 64);
        acc[o] = a;
    }
    int wave = tid >> 6, lane = tid & 63;
    if (lane == 0) {
#pragma unroll
        for (int o = 0; o < 10; ++o) red[wave][o] = acc[o];
    }
    __syncthreads();
    if (tid < 10) {
        float a = (red[0][tid] + red[1][tid]) + (red[2][tid] + red[3][tid]);
        out[((size_t)t * 8 + n) * 10 + tid] = a;
    }
}

// ---------------------------------------------------------------------------
// 6) final spike scan (chunked loads), writes d_out in (n,10,1,1,T) layout
// ---------------------------------------------------------------------------
template <int CH>
__global__ void spike_out_kernel(const float* __restrict__ u, float* __restrict__ out,
                                 int M, int T) {
    int m = blockIdx.x * blockDim.x + threadIdx.x;
    if (m >= M) return;
    float ref[11];
#pragma unroll
    for (int k = 0; k < 11; ++k)
        ref[k] = (float)(-20.0 * (double)k * exp(1.0 - (double)k));
    float r[11];
#pragma unroll
    for (int k = 0; k < 11; ++k) r[k] = 0.f;
    float a[CH], b[CH];
#pragma unroll
    for (int j = 0; j < CH; ++j) a[j] = u[(size_t)j * M + m];
    int NC = T / CH;
    for (int c = 0; c < NC; ++c) {
        if (c + 1 < NC) {
#pragma unroll
            for (int j = 0; j < CH; ++j)
                b[j] = u[(size_t)((c + 1) * CH + j) * M + m];
        }
#pragma unroll
        for (int j = 0; j < CH; ++j) {
            float ue = a[j] + r[0];
            float s = (ue >= THETA) ? 1.0f : 0.0f;
            out[(size_t)m * T + c * CH + j] = s;
#pragma unroll
            for (int k = 0; k < 10; ++k) r[k] = fmaf(s, ref[k + 1], r[k + 1]);
        }
#pragma unroll
        for (int j = 0; j < CH; ++j) a[j] = b[j];
    }
}

// ---------------------------------------------------------------------------
extern "C" void kernel_launch(void* const* d_in, const int* in_sizes, int n_in,
                              void* d_out, int out_size, void* d_ws, size_t ws_size,
                              hipStream_t stream) {
    const float* x   = (const float*)d_in[0];  // (8,2,34,34,300)
    const float* w1  = (const float*)d_in[1];  // (16,2,5,5,1)
    const float* w2  = (const float*)d_in[2];  // (32,16,3,3,1)
    const float* w3  = (const float*)d_in[3];  // (64,32,3,3,1)
    const float* wfc = (const float*)d_in[4];  // (10,64,8,8)
    float* outp = (float*)d_out;               // (8,10,1,1,300)

    float* slotB = (float*)d_ws;               // 39,321,600 floats
    float* slotA = slotB + 39321600;           // 19,660,800 floats
    const int T = 300;
    dim3 blk(256);
    constexpr int TT = 20;                      // 300 = 15 * 20
    constexpr int CH = 10;                      // 300 = 30 * 10

    // 0. xT = transpose(x): [18496][300] -> [300][18496], into slotB
    transpose_kernel<<<dim3(578, 10), dim3(32, 8), 0, stream>>>(x, slotB, 18496, T);
    // 1. p0 = psp(xT) -> slotA   M0 = 18496
    psp_kernel<TT><<<dim3(73, 15), blk, 0, stream>>>(slotB, slotA, 18496);
    // 2. u1 = conv1(p0) -> slotB   (8,16,32,32)
    conv1_lds<<<dim3(8, T), blk, 0, stream>>>(slotA, w1, slotB);
    // 3. s1 = spike(u1) in-place, M=131072
    spike_kernel<CH><<<dim3(512), blk, 0, stream>>>(slotB, 131072, T);
    // 4. u2 = pool(psp(s1)) -> slotA   M=32768
    psppool_kernel<TT><<<dim3(128, 15), blk, 0, stream>>>(slotB, slotA, 8 * 16, 32, 32);
    // 5. s2 = spike(u2)
    spike_kernel<CH><<<dim3(128), blk, 0, stream>>>(slotA, 32768, T);
    // 6. p2 = psp(s2) -> slotB
    psp_kernel<TT><<<dim3(128, 15), blk, 0, stream>>>(slotA, slotB, 32768);
    // 7. u3 = conv2(p2) -> slotA   (8,32,16,16)
    conv2_lds<<<dim3(8, T), blk, 0, stream>>>(slotB, w2, slotA);
    // 8. s3 = spike(u3), M=65536
    spike_kernel<CH><<<dim3(256), blk, 0, stream>>>(slotA, 65536, T);
    // 9. u4 = pool(psp(s3)) -> slotB   M=16384
    psppool_kernel<TT><<<dim3(64, 15), blk, 0, stream>>>(slotA, slotB, 8 * 32, 16, 16);
    // 10. s4 = spike(u4)
    spike_kernel<CH><<<dim3(64), blk, 0, stream>>>(slotB, 16384, T);
    // 11. p4 = psp(s4) -> slotA
    psp_kernel<TT><<<dim3(64, 15), blk, 0, stream>>>(slotB, slotA, 16384);
    // 12. u5 = conv3(p4) -> slotB   (8,64,8,8)
    conv3_lds<<<dim3(2, T, 2), blk, 0, stream>>>(slotA, w3, slotB);
    // 13. s5 = spike(u5), M=32768
    spike_kernel<CH><<<dim3(128), blk, 0, stream>>>(slotB, 32768, T);
    // 14. p5 = psp(s5) -> slotA
    psp_kernel<TT><<<dim3(128, 15), blk, 0, stream>>>(slotB, slotA, 32768);
    // 15. u6 = dense(p5, wfc) -> slotB  [T][8][10]
    dense_kernel<<<dim3(8, T), blk, 0, stream>>>(slotA, wfc, slotB);
    // 16. out = spike(u6), reference (n,o,t) layout
    spike_out_kernel<CH><<<dim3(2), dim3(64), 0, stream>>>(slotB, outp, 80, T);
}